// Round 10
// baseline (64.544 us; speedup 1.0000x reference)
//
#include <hip/hip_runtime.h>

#define NQ 14
#define BLOCK 512
#define NG 28
#define NF2 32  // f32x2 regs per thread: 32 amp-slots x 2 batch elements

typedef float f32x2 __attribute__((ext_vector_type(2)));
__device__ __forceinline__ f32x2 mk2(float a, float b) { f32x2 r; r.x = a; r.y = b; return r; }

// ---------------- compile-time schedule (lazy-CNOT folding) ----------------
struct Sched { unsigned m[NG]; unsigned r[NG]; unsigned fr[NQ]; };

constexpr Sched build_sched() {
  Sched sc{};
  unsigned col[NQ] = {}, rowinv[NQ] = {};
  for (int p = 0; p < NQ; ++p) { col[p] = 1u << p; rowinv[p] = 1u << p; }
  int g = 0;
  for (int l = 0; l < 2; ++l) {
    for (int w = 0; w < NQ; ++w) { int p = NQ - 1 - w; sc.m[g] = col[p]; sc.r[g] = rowinv[p]; ++g; }
    for (int w = 0; w < NQ; ++w) {
      int tgt = (w + 1) % NQ; int pc = NQ - 1 - w, pt = NQ - 1 - tgt;
      col[pc] ^= col[pt]; rowinv[pt] ^= rowinv[pc];
    }
  }
  for (int w = 0; w < NQ; ++w) sc.fr[w] = rowinv[NQ - 1 - w];
  return sc;
}
constexpr Sched SC = build_sched();

// Layer-0 weights absorbed into fill. g14..g27 in ORIGINAL order, bucketed:
//   P1: g14-17 span{9..13}  P2: g18-21 {5..9}  P3: g22-25 {1..5}  P4: g26-27 {0,1,2,12,13}
constexpr unsigned SPAN[4] = {0x3E00u, 0x03E0u, 0x003Eu, 0x3007u};

// local maps: l = 5-bit reg index p (batch lane is NOT part of amp space)
constexpr unsigned lmap1(unsigned v) { return (v >> 9) & 31u; }   // p = i9..13
constexpr unsigned lmap2(unsigned v) { return (v >> 5) & 31u; }   // p = i5..9
constexpr unsigned lmap3(unsigned v) { return (v >> 1) & 31u; }   // p = i1..5
constexpr unsigned lmap4(unsigned v) {                            // p = (i1,i0,i2,i12,i13)
  return ((v >> 1) & 1u) | ((v & 1u) << 1) | (((v >> 2) & 1u) << 2) | (((v >> 12) & 3u) << 3);
}

// ---------- phase layouts: (t<512, p<32) -> amp index i (14 bits) ----------
__host__ __device__ constexpr unsigned i1(unsigned t, unsigned p) { return t | (p << 9); }
__host__ __device__ constexpr unsigned i2(unsigned t, unsigned p) {
  return (t & 31u) | (p << 5) | ((t >> 5) << 10);
}
__host__ __device__ constexpr unsigned i3(unsigned t, unsigned p) {
  return (t & 1u) | (p << 1) | ((t >> 1) << 6);
}
__host__ __device__ constexpr unsigned i4(unsigned t, unsigned p) {
  return ((p >> 1) & 1u) | ((p & 1u) << 1) | (((p >> 2) & 1u) << 2) | ((t & 511u) << 3)
       | (((p >> 3) & 3u) << 12);
}
__host__ __device__ constexpr unsigned base1(unsigned t) { return t; }
__host__ __device__ constexpr unsigned base2(unsigned t) { return (t & 31u) | ((t >> 5) << 10); }
__host__ __device__ constexpr unsigned base3(unsigned t) { return (t & 1u) | ((t >> 1) << 6); }
__host__ __device__ constexpr unsigned base4(unsigned t) { return t << 3; }

// ---------- canonical storage maps: f32x2-slot address of amp i ----------
__host__ __device__ constexpr unsigned s1(unsigned i) {  // T1 pair bit = i9
  return ((i >> 9) & 1u) | (((i & 511u) | (((i >> 10) & 15u) << 9)) << 1);
}
__host__ __device__ constexpr unsigned s2(unsigned i) {  // T2 pair bit = i5
  const unsigned f = (i & 1u) | (((((i >> 1) ^ (i >> 6)) & 1u)) << 1)
                   | (((((i >> 2) ^ (i >> 7)) & 1u)) << 2) | (((i >> 3) & 3u) << 3)
                   | (((i >> 6) & 15u) << 5) | (((i >> 10) & 15u) << 9);
  return ((i >> 5) & 1u) | (f << 1);
}
__host__ __device__ constexpr unsigned s3(unsigned i) {  // T3 pair bit = i1
  const unsigned f = ((i >> 6) & 7u) | ((i & 1u) << 3) | (((i >> 2) & 1u) << 4)
                   | (((i >> 3) & 7u) << 5) | (((i >> 9) & 1u) << 8) | (((i >> 10) & 15u) << 9);
  return ((i >> 1) & 1u) | (f << 1);
}

// ---------- device float4-index decompositions (checked vs canonical) ----------
__host__ __device__ constexpr unsigned W1(unsigned t, unsigned j) {
  return (t & 511u) | (j << 9);
}
__host__ __device__ constexpr unsigned R1(unsigned t, unsigned k) {
  return (t & 31u) | (k << 5) | ((t >> 5) << 9);
}
__host__ __device__ constexpr unsigned W2(unsigned t, unsigned j) {
  return (t & 1u) | (((((t >> 1) ^ j) & 1u)) << 1) | (((((t >> 2) ^ (j >> 1)) & 1u)) << 2)
       | (((t >> 3) & 3u) << 3) | (j << 5) | ((t >> 5) << 9);
}
__host__ __device__ constexpr unsigned R2(unsigned t, unsigned k) {
  return (t & 1u) | (((((t >> 1) ^ k) & 1u)) << 1) | (((((t >> 2) ^ (k >> 1)) & 1u)) << 2)
       | (((k >> 2) & 3u) << 3) | (((t >> 1) & 15u) << 5) | (((t >> 5) & 15u) << 9);
}
__host__ __device__ constexpr unsigned W3(unsigned t, unsigned j) {
  return ((t >> 1) & 7u) | ((t & 1u) << 3) | ((j & 1u) << 4) | (((j >> 1) & 7u) << 5)
       | (((t >> 4) & 1u) << 8) | (((t >> 5) & 15u) << 9);
}
__host__ __device__ constexpr unsigned R3(unsigned t, unsigned k) {
  return ((t >> 3) & 7u) | ((k & 1u) << 3) | (((k >> 1) & 1u) << 4) | ((t & 7u) << 5)
       | (((t >> 6) & 1u) << 8) | (((t >> 7) & 3u) << 9) | (((k >> 2) & 3u) << 11);
}

// ---------------- machine checks ----------------
constexpr bool sched_ok() {
  for (int g = 0; g < 14; ++g)
    if (SC.m[g] != (1u << (13 - g)) || SC.r[g] != (1u << (13 - g))) return false;
  for (int g = 14; g < 28; ++g) {
    const int ph = (g < 18) ? 0 : (g < 22) ? 1 : (g < 26) ? 2 : 3;
    if (SC.m[g] & ~SPAN[ph]) return false;
    unsigned lm = 0, lr = 0;
    if (ph == 0) { lm = lmap1(SC.m[g]); lr = lmap1(SC.r[g]); }
    if (ph == 1) { lm = lmap2(SC.m[g]); lr = lmap2(SC.r[g]); }
    if (ph == 2) { lm = lmap3(SC.m[g]); lr = lmap3(SC.r[g]); }
    if (ph == 3) { lm = lmap4(SC.m[g]); lr = lmap4(SC.r[g]); }
    if (lm == 0 || lm >= 32) return false;
    if (!(__builtin_popcount(lm & lr) & 1)) return false;
  }
  return true;  // original gate order: no commutation requirement
}
static_assert(sched_ok(), "schedule invalid");

constexpr unsigned iP(int ph, unsigned t, unsigned p) {
  return ph == 0 ? i1(t, p) : ph == 1 ? i2(t, p) : ph == 2 ? i3(t, p) : i4(t, p);
}
constexpr bool layouts_ok() {
  for (int ph = 0; ph < 4; ++ph) {
    unsigned acc = 0;
    for (int k = 0; k < 14; ++k) {
      const unsigned t = (k < 9) ? (1u << k) : 0u, p = (k < 9) ? 0u : (1u << (k - 9));
      const unsigned v = iP(ph, t, p);
      if (__builtin_popcount(v) != 1 || (acc & v)) return false;
      acc |= v;
    }
    if (acc != 0x3FFFu) return false;
  }
  // lmap <-> layout correspondence (same p-bit labels) + base disjointness
  for (unsigned k = 0; k < 5; ++k) {
    if (lmap1(i1(0, 1u << k)) != (1u << k)) return false;
    if (lmap2(i2(0, 1u << k)) != (1u << k)) return false;
    if (lmap3(i3(0, 1u << k)) != (1u << k)) return false;
    if (lmap4(i4(0, 1u << k)) != (1u << k)) return false;
  }
  for (unsigned t = 0; t < 512; ++t) {
    if (lmap1(base1(t)) | lmap2(base2(t)) | lmap3(base3(t)) | lmap4(base4(t))) return false;
    if (base1(t) != i1(t, 0) || base2(t) != i2(t, 0)) return false;
    if (base3(t) != i3(t, 0) || base4(t) != i4(t, 0)) return false;
  }
  return true;
}
static_assert(layouts_ok(), "phase layouts invalid");

constexpr bool stmap_bij(int which) {
  bool hit[16384] = {};
  for (unsigned i = 0; i < 16384; ++i) {
    const unsigned a = which == 0 ? s1(i) : which == 1 ? s2(i) : s3(i);
    if (a >= 16384u || hit[a]) return false;
    hit[a] = true;
  }
  return true;
}
static_assert(stmap_bij(0), "s1 not bijective");
static_assert(stmap_bij(1), "s2 not bijective");
static_assert(stmap_bij(2), "s3 not bijective");

// device decomposition == canonical map, exhaustive (all t, all 16 steps, both slots)
constexpr bool chk(int pat, unsigned t0, unsigned t1) {
  for (unsigned t = t0; t < t1; ++t)
    for (unsigned k = 0; k < 16; ++k)
      for (unsigned q = 0; q < 2; ++q) {
        unsigned a = 0, b = 0;
        if (pat == 0) { a = s1(i1(t, 2 * k + q)); b = 2u * W1(t, k) + q; }
        if (pat == 1) { a = s1(i2(t, k | (q << 4))); b = 2u * R1(t, k) + q; }
        if (pat == 2) { a = s2(i2(t, 2 * k + q)); b = 2u * W2(t, k) + q; }
        if (pat == 3) { a = s2(i3(t, k | (q << 4))); b = 2u * R2(t, k) + q; }
        if (pat == 4) { a = s3(i3(t, 2 * k + q)); b = 2u * W3(t, k) + q; }
        if (pat == 5) { a = s3(i4(t, 2 * k + q)); b = 2u * R3(t, k) + q; }
        if (a != b || a >= 16384u) return false;
      }
  return true;
}
static_assert(chk(0, 0, 256) && chk(0, 256, 512), "T1w addr");
static_assert(chk(1, 0, 256) && chk(1, 256, 512), "T1r addr");
static_assert(chk(2, 0, 256) && chk(2, 256, 512), "T2w addr");
static_assert(chk(3, 0, 256) && chk(3, 256, 512), "T2r addr");
static_assert(chk(4, 0, 256) && chk(4, 256, 512), "T3w addr");
static_assert(chk(5, 0, 256) && chk(5, 256, 512), "T3r addr");

// bank balance: every pattern is b128; floor = 8 lanes per float4 bank-group
constexpr bool banks_ok(int pat) {
  for (unsigned W = 0; W < 8; ++W)
    for (unsigned k = 0; k < 16; ++k) {
      int cnt[8] = {};
      for (unsigned l = 0; l < 64; ++l) {
        const unsigned t = W * 64u + l;
        const unsigned F = pat == 0 ? W1(t, k) : pat == 1 ? R1(t, k)
                         : pat == 2 ? W2(t, k) : pat == 3 ? R2(t, k)
                         : pat == 4 ? W3(t, k) : R3(t, k);
        if (++cnt[F & 7u] > 8) return false;
      }
    }
  return true;
}
static_assert(banks_ok(0), "T1w banks");
static_assert(banks_ok(1), "T1r banks");
static_assert(banks_ok(2), "T2w banks");
static_assert(banks_ok(3), "T2r banks");
static_assert(banks_ok(4), "T3w banks");
static_assert(banks_ok(5), "T3r banks");

// ---------------- packed register butterfly (pure 5-bit reg space) ----------------
// Both f32x2 lanes = two batch elements: identical coefficients, no lane crossing.
template <unsigned MU, unsigned RHO>
__device__ __forceinline__ void gate_pk(f32x2* v, const float cg, const float sb) {
  static_assert(MU > 0 && MU < 32, "mu");
  const f32x2 C = mk2(cg, cg);
  constexpr unsigned LSB = MU & (0u - MU);
#pragma unroll
  for (unsigned p = 0; p < NF2; ++p) {
    if (p & LSB) continue;
    const unsigned q = p ^ MU;
    const float s = (__builtin_popcount(p & RHO) & 1) ? -sb : sb;
    const f32x2 Sp = mk2(s, s);
    const f32x2 Xp = v[p], Xq = v[q];
    v[p] = C * Xp - Sp * Xq;
    v[q] = C * Xq + Sp * Xp;  // sigma(q) = -sigma(p): parity(MU&RHO)==1 asserted
  }
}

__global__ __launch_bounds__(BLOCK, 2) void qnn_kernel(
    const float* __restrict__ x, const float* __restrict__ wts,
    float* __restrict__ out) {
  extern __shared__ float4 F4[];          // 128 KB dynamic LDS
  f32x2* const Fv = (f32x2*)F4;
  const unsigned t = threadIdx.x;
  const int b = blockIdx.x;               // handles batch elements 2b (.x), 2b+1 (.y)

  f32x2 v2[NF2];

  // ---- Fill: RY(x + weights[0]) product state for BOTH elements, P1 layout ----
  // amp bit (13-w) <-> wire w: t bits 0..8 = wires 13..5; p bit k (i9+k) = wire 4-k.
  {
    f32x2 ca[NQ], sa[NQ];
#pragma unroll
    for (int w = 0; w < NQ; ++w) {
      const float a0 = 0.5f * (x[(2 * b) * NQ + w] + wts[w]);
      const float a1 = 0.5f * (x[(2 * b + 1) * NQ + w] + wts[w]);
      sa[w] = mk2(__sinf(a0), __sinf(a1));
      ca[w] = mk2(__cosf(a0), __cosf(a1));
    }
    f32x2 pl = mk2(1.0f, 1.0f);
#pragma unroll
    for (int bb = 0; bb < 9; ++bb) pl = pl * (((t >> bb) & 1) ? sa[13 - bb] : ca[13 - bb]);
    v2[0] = pl;
#pragma unroll
    for (int k = 0; k < 5; ++k) {
      const int K = 1 << k;
      const f32x2 sk = sa[4 - k], ck = ca[4 - k];
#pragma unroll
      for (int j = K - 1; j >= 0; --j) {
        v2[j | K] = v2[j] * sk;
        v2[j] = v2[j] * ck;
      }
    }
  }

#define RUN_GATE(LM, G, BASEPAR)                                          \
  {                                                                       \
    const float ang = 0.5f * wts[G];                                      \
    const float sn = __sinf(ang), cs = __cosf(ang);                       \
    const float sb =                                                      \
        (__builtin_popcount((BASEPAR) & SC.r[G]) & 1) ? -sn : sn;         \
    gate_pk<LM(SC.m[G]), LM(SC.r[G])>(v2, cs, sb);                        \
  }

#define PACK2(j) mk2f4(v2[2 * (j)], v2[2 * (j) + 1])
  // float4 = {slot even, slot odd} (each slot is a batch-pair f32x2)
#define STORE_PAIR(F, j)                                                  \
  {                                                                       \
    float4 w4;                                                            \
    w4.x = v2[2 * (j)].x; w4.y = v2[2 * (j)].y;                           \
    w4.z = v2[2 * (j) + 1].x; w4.w = v2[2 * (j) + 1].y;                   \
    F4[(F)] = w4;                                                         \
  }

  // ---------------- Phase 1: span {9..13} ----------------
  {
    const unsigned bs = base1(t);
    RUN_GATE(lmap1, 14, bs) RUN_GATE(lmap1, 15, bs)
    RUN_GATE(lmap1, 16, bs) RUN_GATE(lmap1, 17, bs)
#pragma unroll
    for (unsigned j = 0; j < 16; ++j) STORE_PAIR(W1(t, j), j)
  }
  __syncthreads();  // A

  // ---------------- Phase 2: span {5..9} ----------------
  {
    const unsigned bs = base2(t);
#pragma unroll
    for (unsigned k = 0; k < 16; ++k) {  // pairs (k, k|16) over p4=i9
      const float4 r4 = F4[R1(t, k)];
      v2[k] = mk2(r4.x, r4.y);
      v2[k | 16] = mk2(r4.z, r4.w);
    }
    RUN_GATE(lmap2, 18, bs) RUN_GATE(lmap2, 19, bs)
    RUN_GATE(lmap2, 20, bs) RUN_GATE(lmap2, 21, bs)
  }
  __syncthreads();  // B: T1 reads drained
  {
#pragma unroll
    for (unsigned j = 0; j < 16; ++j) STORE_PAIR(W2(t, j), j)
  }
  __syncthreads();  // C

  // ---------------- Phase 3: span {1..5} ----------------
  {
    const unsigned bs = base3(t);
#pragma unroll
    for (unsigned k = 0; k < 16; ++k) {  // pairs (k, k|16) over p4=i5
      const float4 r4 = F4[R2(t, k)];
      v2[k] = mk2(r4.x, r4.y);
      v2[k | 16] = mk2(r4.z, r4.w);
    }
    RUN_GATE(lmap3, 22, bs) RUN_GATE(lmap3, 23, bs)
    RUN_GATE(lmap3, 24, bs) RUN_GATE(lmap3, 25, bs)
  }
  __syncthreads();  // D: T2 reads drained
  {
#pragma unroll
    for (unsigned j = 0; j < 16; ++j) STORE_PAIR(W3(t, j), j)
  }
  __syncthreads();  // E

  // -------- Phase 4: span {0,1,2,12,13} + measurement --------
  f32x2 ex2[NQ];
  {
    const unsigned bs = base4(t);
#pragma unroll
    for (unsigned k = 0; k < 16; ++k) {  // pairs (2k, 2k+1) over p0=i1
      const float4 r4 = F4[R3(t, k)];
      v2[2 * k] = mk2(r4.x, r4.y);
      v2[2 * k + 1] = mk2(r4.z, r4.w);
    }
    RUN_GATE(lmap4, 26, bs) RUN_GATE(lmap4, 27, bs)

    // q = v^2 (both elements); full WHT over 5 reg bits
#pragma unroll
    for (unsigned p = 0; p < NF2; ++p) v2[p] = v2[p] * v2[p];
#pragma unroll
    for (int k = 0; k < 5; ++k) {
      const unsigned K = 1u << k;
#pragma unroll
      for (unsigned p = 0; p < NF2; ++p) {
        if (p & K) continue;
        const f32x2 A = v2[p], Bv = v2[p ^ K];
        v2[p] = A + Bv;
        v2[p ^ K] = A - Bv;
      }
    }
#pragma unroll
    for (int w = 0; w < NQ; ++w) {
      const f32x2 coef = v2[lmap4(SC.fr[w])];
      const int tf = __builtin_popcount(bs & SC.fr[w]) & 1;
      ex2[w] = tf ? mk2(-coef.x, -coef.y) : coef;
    }
  }
  __syncthreads();  // F: T3 reads drained; LDS reusable

  // ---------------- two-stage LDS reduction (f32x2 partials) ----------------
  // Stage A: thread r, q=0..6: float4 at r*8 + (q^(r&7)) = {ex2[2q], ex2[2q+1]}
  {
#pragma unroll
    for (unsigned q = 0; q < 7; ++q) {
      float4 w4;
      w4.x = ex2[2 * q].x; w4.y = ex2[2 * q].y;
      w4.z = ex2[2 * q + 1].x; w4.w = ex2[2 * q + 1].y;
      F4[t * 8u + (q ^ (t & 7u))] = w4;
    }
  }
  __syncthreads();  // G
  {
    const unsigned w = t & 15u, g = t >> 4;  // g < 32
    if (w < NQ) {
      f32x2 acc = mk2(0.0f, 0.0f);
#pragma unroll
      for (unsigned k = 0; k < 16; ++k) {
        const unsigned rr = g * 16u + k;  // rr&7 == k&7
        acc = acc + Fv[16u * rr + 2u * ((w >> 1) ^ (k & 7u)) + (w & 1u)];
      }
      Fv[8192u + w * 32u + g] = acc;
    }
  }
  __syncthreads();  // H
  if (t < NQ) {
    f32x2 r = mk2(0.0f, 0.0f);
#pragma unroll
    for (unsigned j = 0; j < 16; ++j) {
      const float4 r4 = F4[4096u + t * 16u + j];
      r = r + mk2(r4.x, r4.y) + mk2(r4.z, r4.w);
    }
    out[(2 * b) * NQ + t] = r.x;
    out[(2 * b + 1) * NQ + t] = r.y;
  }
#undef RUN_GATE
#undef STORE_PAIR
#undef PACK2
}

extern "C" void kernel_launch(void* const* d_in, const int* in_sizes, int n_in,
                              void* d_out, int out_size, void* d_ws, size_t ws_size,
                              hipStream_t stream) {
  const float* x = (const float*)d_in[0];        // (B, 14) fp32
  const float* weights = (const float*)d_in[1];  // (2, 14) fp32
  float* out = (float*)d_out;                    // (B, 14) fp32
  const int B = in_sizes[0] / NQ;
  const size_t lds_bytes = 131072;               // 128 KB: 16384 packed f32x2 amps
  hipFuncSetAttribute((const void*)qnn_kernel,
                      hipFuncAttributeMaxDynamicSharedMemorySize, (int)lds_bytes);
  qnn_kernel<<<B / 2, BLOCK, lds_bytes, stream>>>(x, weights, out);
}

// Round 11
// 54.880 us; speedup vs baseline: 1.1761x; 1.1761x over previous
//
#include <hip/hip_runtime.h>

#define NQ 14

// ================= single-source closed-form machinery =================
// Ring C = CNOT(0->1), CNOT(1->2), ..., CNOT(n-1->0) applied in that order.
// Heisenberg pullback of Z_w through the ring -> Z-string mask (phase-free):
template <int N>
__host__ __device__ constexpr unsigned ringZ(unsigned w) {
  unsigned z = 1u << w;
  for (int c = N - 1; c >= 0; --c) {
    const int t = (c + 1) % N;
    if ((z >> t) & 1u) z ^= 1u << c;
  }
  return z;
}

// Chain contraction for one (output mask m, boundary bits beta, beta').
//   a[j],b[j] = cos,sin(theta_j/2)   (theta = x + w0)
//   c1[j],s1[j] = cos,sin(w1_j)      (full angle)
// E_w = sum over (beta,beta') of chainE(...). Derivation:
//   E_w = sum_{g,g'} prod_j K^w_j(g_j,g'_j) prod_j amp_j(rho_j(g)) amp_j(rho_j(g'))
//   rho_0 = g_0^g_{n-1} (=beta), rho_1 = g_1^beta, rho_j = g_{j-1}^g_j (j>=2)
//   K_j = delta (mask bit 0) or {c,-s;-s,-c} (mask bit 1); site 1 at init,
//   sites 2..n-1 as transfer steps, site 0 at ring closure (g_0 = g_{n-1}^beta).
template <int N, typename T>
__host__ __device__ constexpr T chainE(const T* a, const T* b, const T* c1, const T* s1,
                                       unsigned m, unsigned beta, unsigned betap) {
  const T p0 = beta ? b[1] : a[1], p1 = beta ? a[1] : b[1];
  const T q0 = betap ? b[1] : a[1], q1 = betap ? a[1] : b[1];
  T v00 = p0 * q0, v01 = p0 * q1, v10 = p1 * q0, v11 = p1 * q1;
  {
    const bool mb = ((m >> 1) & 1u) != 0;
    const T kd = mb ? c1[1] : T(1);
    const T kn = mb ? -c1[1] : T(1);
    const T ko = mb ? -s1[1] : T(0);
    v00 *= kd; v01 *= ko; v10 *= ko; v11 *= kn;
  }
#pragma unroll
  for (int j = 2; j < N; ++j) {
    const T aj = a[j], bj = b[j];
    const T t00 = aj * v00 + bj * v10, t01 = aj * v01 + bj * v11;
    const T t10 = aj * v10 + bj * v00, t11 = aj * v11 + bj * v01;
    T u00 = aj * t00 + bj * t01, u01 = aj * t01 + bj * t00;
    T u10 = aj * t10 + bj * t11, u11 = aj * t11 + bj * t10;
    const bool mb = ((m >> j) & 1u) != 0;
    const T kd = mb ? c1[j] : T(1);
    const T kn = mb ? -c1[j] : T(1);
    const T ko = mb ? -s1[j] : T(0);
    v00 = u00 * kd; v01 = u01 * ko; v10 = u10 * ko; v11 = u11 * kn;
  }
  // closure at site 0: g_0 = g^beta, g'_0 = g'^betap
  T S;
  if (m & 1u) {
    const T c = c1[0], s = s1[0];
    const bool same = (beta == betap);
    const T k00 = same ? (beta ? -c : c) : -s;
    const T k11 = same ? (beta ? c : -c) : -s;
    const T k01 = !same ? (beta ? -c : c) : -s;
    const T k10 = !same ? (beta ? c : -c) : -s;
    S = v00 * k00 + v01 * k01 + v10 * k10 + v11 * k11;
  } else {
    S = (beta == betap) ? (v00 + v11) : (v01 + v10);
  }
  const T f0 = beta ? b[0] : a[0];
  const T f1 = betap ? b[0] : a[0];
  return f0 * f1 * S;
}

// ================= compile-time verification vs brute force =================
constexpr double c_sin(double x) {
  constexpr double PI = 3.14159265358979323846;
  while (x > PI) x -= 2.0 * PI;
  while (x < -PI) x += 2.0 * PI;
  double term = x, sum = x;
  const double x2 = x * x;
  for (int k = 1; k <= 15; ++k) { term *= -x2 / double((2 * k) * (2 * k + 1)); sum += term; }
  return sum;
}
constexpr double c_cos(double x) { return c_sin(x + 1.5707963267948966); }

// Independent brute-force simulation of the REFERENCE circuit (bit j = wire j),
// compared against the SAME chainE/ringZ the device uses.
template <int N>
constexpr bool verify(unsigned seed) {
  constexpr int SZ = 1 << N;
  double xa[N] = {}, w0[N] = {}, w1[N] = {};
  unsigned s = seed;
  for (int j = 0; j < N; ++j) { s = s * 1664525u + 1013904223u; xa[j] = 6.283185307179586 * double((s >> 8) & 0xFFFFu) / 65536.0; }
  for (int j = 0; j < N; ++j) { s = s * 1664525u + 1013904223u; w0[j] = 6.283185307179586 * double((s >> 8) & 0xFFFFu) / 65536.0; }
  for (int j = 0; j < N; ++j) { s = s * 1664525u + 1013904223u; w1[j] = 6.283185307179586 * double((s >> 8) & 0xFFFFu) / 65536.0; }
  double st[SZ] = {};
  st[0] = 1.0;
  for (int pass = 0; pass < 3; ++pass) {
    const double* ang = pass == 0 ? xa : (pass == 1 ? w0 : w1);
    for (int w = 0; w < N; ++w) {  // RY layer
      const double ch = c_cos(0.5 * ang[w]), sh = c_sin(0.5 * ang[w]);
      for (int i = 0; i < SZ; ++i) {
        if ((i >> w) & 1) continue;
        const int j2 = i | (1 << w);
        const double A0 = st[i], A1 = st[j2];
        st[i] = ch * A0 - sh * A1;
        st[j2] = sh * A0 + ch * A1;
      }
    }
    if (pass >= 1) {  // CNOT ring, w -> w+1 mod N, in order
      for (int w = 0; w < N; ++w) {
        const int c = w, t = (w + 1) % N;
        for (int i = 0; i < SZ; ++i) {
          if (((i >> c) & 1) && !((i >> t) & 1)) {
            const int j2 = i ^ (1 << t);
            const double tmp = st[i];
            st[i] = st[j2];
            st[j2] = tmp;
          }
        }
      }
    }
  }
  double a[N] = {}, b[N] = {}, c1[N] = {}, s1[N] = {};
  for (int j = 0; j < N; ++j) {
    a[j] = c_cos(0.5 * (xa[j] + w0[j]));
    b[j] = c_sin(0.5 * (xa[j] + w0[j]));
    c1[j] = c_cos(w1[j]);
    s1[j] = c_sin(w1[j]);
  }
  for (int w = 0; w < N; ++w) {
    double Eref = 0.0;
    for (int i = 0; i < SZ; ++i) Eref += st[i] * st[i] * (((i >> w) & 1) ? -1.0 : 1.0);
    double E = 0.0;
    for (unsigned bb = 0; bb < 4; ++bb)
      E += chainE<N, double>(a, b, c1, s1, ringZ<N>((unsigned)w), bb >> 1, bb & 1u);
    const double d = E > Eref ? E - Eref : Eref - E;
    if (d > 1e-9) return false;
  }
  return true;
}
static_assert(verify<3>(1u), "closed form != brute force at n=3");
static_assert(verify<4>(1234u), "closed form != brute force at n=4");
static_assert(verify<5>(98765u), "closed form != brute force at n=5");
static_assert(verify<6>(555u), "closed form != brute force at n=6");
static_assert(verify<5>(31337u), "closed form != brute force at n=5 (seed 2)");

// masks for n=14, from the same single-source ringZ
struct MWTab { unsigned v[NQ]; };
constexpr MWTab mk_mw() {
  MWTab t{};
  for (int w = 0; w < NQ; ++w) t.v[w] = ringZ<NQ>((unsigned)w);
  return t;
}
constexpr MWTab MWT = mk_mw();

// ================= device kernel =================
// Block = 256 threads = 4 batch elements x 64 lanes.
// Lane role: w = lane>>2 (output wire, <14), bb = lane&3 = (beta,beta').
__global__ __launch_bounds__(256) void qnn_kernel(const float* __restrict__ x,
                                                  const float* __restrict__ wts,
                                                  float* __restrict__ out, int B) {
  __shared__ float sa[4][NQ], sb[4][NQ], sc[NQ], ss[NQ];
  const unsigned tid = threadIdx.x;
  const unsigned eL = tid >> 6, lane = tid & 63u;
  const int e = blockIdx.x * 4 + (int)eL;

  if (lane < NQ && e < B) {  // per-element theta/2 trigs
    const float th = x[e * NQ + lane] + wts[lane];
    __sincosf(0.5f * th, &sb[eL][lane], &sa[eL][lane]);
  }
  if (tid >= NQ && tid < 2 * NQ) {  // per-block w1 full-angle trigs
    const unsigned j = tid - NQ;
    __sincosf(wts[NQ + j], &ss[j], &sc[j]);
  }
  __syncthreads();

  const unsigned w = lane >> 2, bb = lane & 3u;
  float E = 0.0f;
  if (w < NQ && e < B) {
    E = chainE<NQ, float>(sa[eL], sb[eL], sc, ss, MWT.v[w], bb >> 1, bb & 1u);
  }
  // sum the 4 boundary cases
  E += __shfl_xor(E, 1, 64);
  E += __shfl_xor(E, 2, 64);
  if (w < NQ && bb == 0 && e < B) out[e * NQ + w] = E;
}

extern "C" void kernel_launch(void* const* d_in, const int* in_sizes, int n_in,
                              void* d_out, int out_size, void* d_ws, size_t ws_size,
                              hipStream_t stream) {
  const float* x = (const float*)d_in[0];        // (B, 14) fp32
  const float* weights = (const float*)d_in[1];  // (2, 14) fp32
  float* out = (float*)d_out;                    // (B, 14) fp32
  const int B = in_sizes[0] / NQ;
  const int grid = (B + 3) / 4;
  qnn_kernel<<<grid, 256, 0, stream>>>(x, weights, out, B);
}